// Round 1
// baseline (34410.883 us; speedup 1.0000x reference)
//
#include <hip/hip_runtime.h>

// SimpleDHSRNN fused forward for MI355X.
// B=8192 elements, T=196 steps. Block = 512 threads = 16 slices x 32 elems.
// grid = 256 blocks (1 per CU). All 196 recurrent steps run inside the kernel.

#define NTHR 512
#define E    32      // batch elements per block
#define NSL  16      // output slices per block
#define T_STEPS 196

#define JA 4   // cell1 branch outs per slice (64/16)
#define OB 2   // cell1 hidden outs per slice (32/16)
#define JC 8   // cell2 branch outs per slice (128/16)
#define OD 4   // cell2 hidden outs per slice (64/16)

__global__ __launch_bounds__(NTHR, 1)
void dhsrnn_fused(const float* __restrict__ x,
                  const float* __restrict__ r1_bw, const float* __restrict__ r1_bb,
                  const float* __restrict__ r1_ow, const float* __restrict__ r1_ob,
                  const float* __restrict__ r2_bw, const float* __restrict__ r2_bb,
                  const float* __restrict__ r2_ow, const float* __restrict__ r2_ob,
                  const float* __restrict__ cw,    const float* __restrict__ cb,
                  float* __restrict__ out)
{
    // W1b repacked: row j (flat k*32+o) = [w_h0..w_h31, w_x, 0,0,0], stride 36 (16B-aligned rows)
    __shared__ __align__(16) float W1b[64 * 36];
    __shared__ float h1s[32 * E];    // [dim][elem]
    __shared__ float h2s[64 * E];
    __shared__ float n1s[64 * E];    // ns1 flat
    __shared__ float n2s[128 * E];   // ns2 flat

    const int tid = threadIdx.x;
    const int e   = tid & (E - 1);
    const int sl  = tid >> 5;
    const int b   = blockIdx.x * E + e;

    // ---- one-time: repack r1_bw into LDS, zero states ----
    for (int idx = tid; idx < 64 * 36; idx += NTHR) {
        int row = idx / 36;
        int col = idx - row * 36;
        float v = 0.0f;
        if (col < 32)       v = r1_bw[row * 33 + 1 + col];  // h-weights
        else if (col == 32) v = r1_bw[row * 33 + 0];        // x-weight
        W1b[idx] = v;
    }
    for (int idx = tid; idx < 32 * E; idx += NTHR) h1s[idx] = 0.0f;
    for (int idx = tid; idx < 64 * E; idx += NTHR) h2s[idx] = 0.0f;
    __syncthreads();

    // ---- per-lane persistent state + preloaded biases/alphas ----
    float s1[JA], s2[JC];
#pragma unroll
    for (int jj = 0; jj < JA; ++jj) s1[jj] = 0.0f;
#pragma unroll
    for (int jj = 0; jj < JC; ++jj) s2[jj] = 0.0f;

    float b1v[JA], a1v[JA], wxv[JA];
#pragma unroll
    for (int jj = 0; jj < JA; ++jj) {
        int j = sl * JA + jj;
        b1v[jj] = r1_bb[j];
        a1v[jj] = (j < 32) ? 0.3f : 0.7f;
        wxv[jj] = W1b[j * 36 + 32];
    }
    float b2v[JC], a2v[JC];
#pragma unroll
    for (int jj = 0; jj < JC; ++jj) {
        int j = sl * JC + jj;
        b2v[jj] = r2_bb[j];
        a2v[jj] = (j < 64) ? 0.3f : 0.7f;
    }
    float b1ov[OB];
#pragma unroll
    for (int oo = 0; oo < OB; ++oo) b1ov[oo] = r1_ob[sl * OB + oo];
    float b2ov[OD];
#pragma unroll
    for (int oo = 0; oo < OD; ++oo) b2ov[oo] = r2_ob[sl * OD + oo];

    const float* pW1o = r1_ow + (sl * OB) * 64;
    const float* pW2b = r2_bw + (sl * JC) * 96;
    const float* pW2o = r2_ow + (sl * OD) * 128;

    // ---- time loop ----
    for (int t = 0; t < T_STEPS; ++t) {
        // Stage A: cell1 branch outs (bo1), EMA update s1, write ns1 flat
        float xv = x[b * 784 + 4 * t];
        float accA[JA];
#pragma unroll
        for (int jj = 0; jj < JA; ++jj) accA[jj] = b1v[jj] + wxv[jj] * xv;
#pragma unroll
        for (int i4 = 0; i4 < 32; i4 += 4) {
            float f0 = h1s[(i4 + 0) * E + e];
            float f1 = h1s[(i4 + 1) * E + e];
            float f2 = h1s[(i4 + 2) * E + e];
            float f3 = h1s[(i4 + 3) * E + e];
#pragma unroll
            for (int jj = 0; jj < JA; ++jj) {
                const float4 w = *reinterpret_cast<const float4*>(&W1b[(sl * JA + jj) * 36 + i4]);
                accA[jj] += w.x * f0 + w.y * f1 + w.z * f2 + w.w * f3;
            }
        }
#pragma unroll
        for (int jj = 0; jj < JA; ++jj) {
            float ns = a1v[jj] * s1[jj] + (1.0f - a1v[jj]) * accA[jj];
            s1[jj] = ns;
            n1s[(sl * JA + jj) * E + e] = ns;
        }
        __syncthreads();

        // Stage B: h1 = relu(ns1_flat @ ow1^T + ob1)
        float accB[OB];
#pragma unroll
        for (int oo = 0; oo < OB; ++oo) accB[oo] = b1ov[oo];
        for (int i4 = 0; i4 < 64; i4 += 4) {
            float f0 = n1s[(i4 + 0) * E + e];
            float f1 = n1s[(i4 + 1) * E + e];
            float f2 = n1s[(i4 + 2) * E + e];
            float f3 = n1s[(i4 + 3) * E + e];
#pragma unroll
            for (int oo = 0; oo < OB; ++oo) {
                const float4 w = *reinterpret_cast<const float4*>(pW1o + oo * 64 + i4);
                accB[oo] += w.x * f0 + w.y * f1 + w.z * f2 + w.w * f3;
            }
        }
        __syncthreads();   // h1s reads in stage A done; safe ordering for write below via next barrier
#pragma unroll
        for (int oo = 0; oo < OB; ++oo) {
            h1s[(sl * OB + oo) * E + e] = fmaxf(accB[oo], 0.0f);
        }
        __syncthreads();

        // Stage C: cell2 branch (ci2 = [h1, h2]), EMA update s2, write ns2 flat
        float accC[JC];
#pragma unroll
        for (int jj = 0; jj < JC; ++jj) accC[jj] = b2v[jj];
        for (int i4 = 0; i4 < 32; i4 += 4) {
            float f0 = h1s[(i4 + 0) * E + e];
            float f1 = h1s[(i4 + 1) * E + e];
            float f2 = h1s[(i4 + 2) * E + e];
            float f3 = h1s[(i4 + 3) * E + e];
#pragma unroll
            for (int jj = 0; jj < JC; ++jj) {
                const float4 w = *reinterpret_cast<const float4*>(pW2b + jj * 96 + i4);
                accC[jj] += w.x * f0 + w.y * f1 + w.z * f2 + w.w * f3;
            }
        }
        for (int i4 = 0; i4 < 64; i4 += 4) {
            float f0 = h2s[(i4 + 0) * E + e];
            float f1 = h2s[(i4 + 1) * E + e];
            float f2 = h2s[(i4 + 2) * E + e];
            float f3 = h2s[(i4 + 3) * E + e];
#pragma unroll
            for (int jj = 0; jj < JC; ++jj) {
                const float4 w = *reinterpret_cast<const float4*>(pW2b + jj * 96 + 32 + i4);
                accC[jj] += w.x * f0 + w.y * f1 + w.z * f2 + w.w * f3;
            }
        }
#pragma unroll
        for (int jj = 0; jj < JC; ++jj) {
            float ns = a2v[jj] * s2[jj] + (1.0f - a2v[jj]) * accC[jj];
            s2[jj] = ns;
            n2s[(sl * JC + jj) * E + e] = ns;
        }
        __syncthreads();

        // Stage D: h2 = relu(ns2_flat @ ow2^T + ob2)
        float accD[OD];
#pragma unroll
        for (int oo = 0; oo < OD; ++oo) accD[oo] = b2ov[oo];
        for (int i4 = 0; i4 < 128; i4 += 4) {
            float f0 = n2s[(i4 + 0) * E + e];
            float f1 = n2s[(i4 + 1) * E + e];
            float f2 = n2s[(i4 + 2) * E + e];
            float f3 = n2s[(i4 + 3) * E + e];
#pragma unroll
            for (int oo = 0; oo < OD; ++oo) {
                const float4 w = *reinterpret_cast<const float4*>(pW2o + oo * 128 + i4);
                accD[oo] += w.x * f0 + w.y * f1 + w.z * f2 + w.w * f3;
            }
        }
        __syncthreads();   // orders h2s reads (stage C/D inputs) before writes
#pragma unroll
        for (int oo = 0; oo < OD; ++oo) {
            h2s[(sl * OD + oo) * E + e] = fmaxf(accD[oo], 0.0f);
        }
        __syncthreads();
    }

    // ---- classifier: out[b][c] = h2 . cw[c] + cb[c] ----
    if (sl < 10) {
        float acc = cb[sl];
        for (int i4 = 0; i4 < 64; i4 += 4) {
            float f0 = h2s[(i4 + 0) * E + e];
            float f1 = h2s[(i4 + 1) * E + e];
            float f2 = h2s[(i4 + 2) * E + e];
            float f3 = h2s[(i4 + 3) * E + e];
            const float4 w = *reinterpret_cast<const float4*>(cw + sl * 64 + i4);
            acc += w.x * f0 + w.y * f1 + w.z * f2 + w.w * f3;
        }
        out[b * 10 + sl] = acc;
    }
}

extern "C" void kernel_launch(void* const* d_in, const int* in_sizes, int n_in,
                              void* d_out, int out_size, void* d_ws, size_t ws_size,
                              hipStream_t stream) {
    const float* x     = (const float*)d_in[0];
    const float* r1_bw = (const float*)d_in[1];
    const float* r1_bb = (const float*)d_in[2];
    const float* r1_ow = (const float*)d_in[3];
    const float* r1_ob = (const float*)d_in[4];
    const float* r2_bw = (const float*)d_in[5];
    const float* r2_bb = (const float*)d_in[6];
    const float* r2_ow = (const float*)d_in[7];
    const float* r2_ob = (const float*)d_in[8];
    const float* cw    = (const float*)d_in[9];
    const float* cb    = (const float*)d_in[10];
    float* out = (float*)d_out;

    dim3 grid(8192 / E);
    dim3 block(NTHR);
    hipLaunchKernelGGL(dhsrnn_fused, grid, block, 0, stream,
                       x, r1_bw, r1_bb, r1_ow, r1_ob,
                       r2_bw, r2_bb, r2_ow, r2_ob, cw, cb, out);
}

// Round 2
// 2370.691 us; speedup vs baseline: 14.5151x; 14.5151x over previous
//
#include <hip/hip_runtime.h>

// SimpleDHSRNN fused forward for MI355X — round 2.
// All weights staged in LDS once (97 KB); inner 196-step loop touches only LDS.
// Block = 1024 threads = 32 slices x 32 elems; grid = 256 blocks (1/CU).

#define NTHR 1024
#define E    32      // batch elements per block
#define NSL  32      // output slices per block
#define T_STEPS 196

#define JA 2   // cell1 branch outs per slice (64/32)
#define OB 1   // cell1 hidden outs per slice (32/32)
#define JC 4   // cell2 branch outs per slice (128/32)
#define OD 2   // cell2 hidden outs per slice (64/32)

__global__ __launch_bounds__(NTHR, 1)
void dhsrnn_fused(const float* __restrict__ x,
                  const float* __restrict__ r1_bw, const float* __restrict__ r1_bb,
                  const float* __restrict__ r1_ow, const float* __restrict__ r1_ob,
                  const float* __restrict__ r2_bw, const float* __restrict__ r2_bb,
                  const float* __restrict__ r2_ow, const float* __restrict__ r2_ob,
                  const float* __restrict__ cw,    const float* __restrict__ cb,
                  float* __restrict__ out)
{
    // ---- weights in LDS (staged once) ----
    // W1b repacked: row j = [w_h0..w_h31, w_x, 0,0,0], stride 36 (16B-aligned rows)
    __shared__ __align__(16) float W1b[64 * 36];    //  9.2 KB
    __shared__ __align__(16) float W1o[32 * 64];    //  8.0 KB
    __shared__ __align__(16) float W2b[128 * 96];   // 48.0 KB
    __shared__ __align__(16) float W2o[64 * 128];   // 32.0 KB
    // ---- activations, [dim][elem] layout (lane e -> distinct bank) ----
    __shared__ float h1s[32 * E];    //  4 KB
    __shared__ float h2s[64 * E];    //  8 KB
    __shared__ float n1s[64 * E];    //  8 KB
    __shared__ float n2s[128 * E];   // 16 KB
    // total: 133 KB -> 1 block/CU

    const int tid = threadIdx.x;
    const int e   = tid & (E - 1);
    const int sl  = tid >> 5;        // 0..31
    const int b   = blockIdx.x * E + e;

    // ---- one-time: stage weights into LDS, zero states ----
    for (int idx = tid; idx < 64 * 36; idx += NTHR) {
        int row = idx / 36;
        int col = idx - row * 36;
        float v = 0.0f;
        if (col < 32)       v = r1_bw[row * 33 + 1 + col];  // h-weights
        else if (col == 32) v = r1_bw[row * 33 + 0];        // x-weight
        W1b[idx] = v;
    }
    for (int idx = tid; idx < 32 * 64;  idx += NTHR) W1o[idx] = r1_ow[idx];
    for (int idx = tid; idx < 128 * 96; idx += NTHR) W2b[idx] = r2_bw[idx];
    for (int idx = tid; idx < 64 * 128; idx += NTHR) W2o[idx] = r2_ow[idx];
    for (int idx = tid; idx < 32 * E; idx += NTHR) h1s[idx] = 0.0f;
    for (int idx = tid; idx < 64 * E; idx += NTHR) h2s[idx] = 0.0f;
    __syncthreads();

    // ---- per-lane persistent state + preloaded biases/alphas ----
    float s1[JA], s2[JC];
#pragma unroll
    for (int jj = 0; jj < JA; ++jj) s1[jj] = 0.0f;
#pragma unroll
    for (int jj = 0; jj < JC; ++jj) s2[jj] = 0.0f;

    float b1v[JA], a1v[JA], wxv[JA];
#pragma unroll
    for (int jj = 0; jj < JA; ++jj) {
        int j = sl * JA + jj;
        b1v[jj] = r1_bb[j];
        a1v[jj] = (j < 32) ? 0.3f : 0.7f;
        wxv[jj] = W1b[j * 36 + 32];
    }
    float b2v[JC], a2v[JC];
#pragma unroll
    for (int jj = 0; jj < JC; ++jj) {
        int j = sl * JC + jj;
        b2v[jj] = r2_bb[j];
        a2v[jj] = (j < 64) ? 0.3f : 0.7f;
    }
    float b1ov = r1_ob[sl];          // OB == 1
    float b2ov[OD];
#pragma unroll
    for (int oo = 0; oo < OD; ++oo) b2ov[oo] = r2_ob[sl * OD + oo];

    // ---- time loop (4 barriers/step) ----
    for (int t = 0; t < T_STEPS; ++t) {
        // Stage A: cell1 branch outs, EMA s1, write ns1 flat
        float xv = x[b * 784 + 4 * t];
        float accA[JA];
#pragma unroll
        for (int jj = 0; jj < JA; ++jj) accA[jj] = b1v[jj] + wxv[jj] * xv;
#pragma unroll
        for (int i4 = 0; i4 < 32; i4 += 4) {
            float f0 = h1s[(i4 + 0) * E + e];
            float f1 = h1s[(i4 + 1) * E + e];
            float f2 = h1s[(i4 + 2) * E + e];
            float f3 = h1s[(i4 + 3) * E + e];
#pragma unroll
            for (int jj = 0; jj < JA; ++jj) {
                const float4 w = *reinterpret_cast<const float4*>(&W1b[(sl * JA + jj) * 36 + i4]);
                accA[jj] += w.x * f0 + w.y * f1 + w.z * f2 + w.w * f3;
            }
        }
#pragma unroll
        for (int jj = 0; jj < JA; ++jj) {
            float ns = a1v[jj] * s1[jj] + (1.0f - a1v[jj]) * accA[jj];
            s1[jj] = ns;
            n1s[(sl * JA + jj) * E + e] = ns;
        }
        __syncthreads();   // n1s ready; also fences all stage-A h1s reads

        // Stage B: h1 = relu(ns1 @ ow1^T + ob1)   (OB == 1 row per slice)
        float accB = b1ov;
#pragma unroll
        for (int i4 = 0; i4 < 64; i4 += 4) {
            float f0 = n1s[(i4 + 0) * E + e];
            float f1 = n1s[(i4 + 1) * E + e];
            float f2 = n1s[(i4 + 2) * E + e];
            float f3 = n1s[(i4 + 3) * E + e];
            const float4 w = *reinterpret_cast<const float4*>(&W1o[sl * 64 + i4]);
            accB += w.x * f0 + w.y * f1 + w.z * f2 + w.w * f3;
        }
        h1s[sl * E + e] = fmaxf(accB, 0.0f);   // safe: all h1s readers fenced above
        __syncthreads();   // h1s ready

        // Stage C: cell2 branch (ci2 = [h1, h2]), EMA s2, write ns2 flat
        float accC[JC];
#pragma unroll
        for (int jj = 0; jj < JC; ++jj) accC[jj] = b2v[jj];
#pragma unroll
        for (int i4 = 0; i4 < 32; i4 += 4) {
            float f0 = h1s[(i4 + 0) * E + e];
            float f1 = h1s[(i4 + 1) * E + e];
            float f2 = h1s[(i4 + 2) * E + e];
            float f3 = h1s[(i4 + 3) * E + e];
#pragma unroll
            for (int jj = 0; jj < JC; ++jj) {
                const float4 w = *reinterpret_cast<const float4*>(&W2b[(sl * JC + jj) * 96 + i4]);
                accC[jj] += w.x * f0 + w.y * f1 + w.z * f2 + w.w * f3;
            }
        }
#pragma unroll
        for (int i4 = 0; i4 < 64; i4 += 4) {
            float f0 = h2s[(i4 + 0) * E + e];
            float f1 = h2s[(i4 + 1) * E + e];
            float f2 = h2s[(i4 + 2) * E + e];
            float f3 = h2s[(i4 + 3) * E + e];
#pragma unroll
            for (int jj = 0; jj < JC; ++jj) {
                const float4 w = *reinterpret_cast<const float4*>(&W2b[(sl * JC + jj) * 96 + 32 + i4]);
                accC[jj] += w.x * f0 + w.y * f1 + w.z * f2 + w.w * f3;
            }
        }
#pragma unroll
        for (int jj = 0; jj < JC; ++jj) {
            float ns = a2v[jj] * s2[jj] + (1.0f - a2v[jj]) * accC[jj];
            s2[jj] = ns;
            n2s[(sl * JC + jj) * E + e] = ns;
        }
        __syncthreads();   // n2s ready; also fences all stage-C h2s reads

        // Stage D: h2 = relu(ns2 @ ow2^T + ob2)
        float accD[OD];
#pragma unroll
        for (int oo = 0; oo < OD; ++oo) accD[oo] = b2ov[oo];
#pragma unroll
        for (int i4 = 0; i4 < 128; i4 += 4) {
            float f0 = n2s[(i4 + 0) * E + e];
            float f1 = n2s[(i4 + 1) * E + e];
            float f2 = n2s[(i4 + 2) * E + e];
            float f3 = n2s[(i4 + 3) * E + e];
#pragma unroll
            for (int oo = 0; oo < OD; ++oo) {
                const float4 w = *reinterpret_cast<const float4*>(&W2o[(sl * OD + oo) * 128 + i4]);
                accD[oo] += w.x * f0 + w.y * f1 + w.z * f2 + w.w * f3;
            }
        }
#pragma unroll
        for (int oo = 0; oo < OD; ++oo) {
            h2s[(sl * OD + oo) * E + e] = fmaxf(accD[oo], 0.0f);   // safe: readers fenced above
        }
        __syncthreads();   // h2s ready
    }

    // ---- classifier: out[b][c] = h2 . cw[c] + cb[c] ----
    if (sl < 10) {
        float acc = cb[sl];
#pragma unroll
        for (int i4 = 0; i4 < 64; i4 += 4) {
            float f0 = h2s[(i4 + 0) * E + e];
            float f1 = h2s[(i4 + 1) * E + e];
            float f2 = h2s[(i4 + 2) * E + e];
            float f3 = h2s[(i4 + 3) * E + e];
            const float4 w = *reinterpret_cast<const float4*>(cw + sl * 64 + i4);
            acc += w.x * f0 + w.y * f1 + w.z * f2 + w.w * f3;
        }
        out[b * 10 + sl] = acc;
    }
}

extern "C" void kernel_launch(void* const* d_in, const int* in_sizes, int n_in,
                              void* d_out, int out_size, void* d_ws, size_t ws_size,
                              hipStream_t stream) {
    const float* x     = (const float*)d_in[0];
    const float* r1_bw = (const float*)d_in[1];
    const float* r1_bb = (const float*)d_in[2];
    const float* r1_ow = (const float*)d_in[3];
    const float* r1_ob = (const float*)d_in[4];
    const float* r2_bw = (const float*)d_in[5];
    const float* r2_bb = (const float*)d_in[6];
    const float* r2_ow = (const float*)d_in[7];
    const float* r2_ob = (const float*)d_in[8];
    const float* cw    = (const float*)d_in[9];
    const float* cb    = (const float*)d_in[10];
    float* out = (float*)d_out;

    dim3 grid(8192 / E);
    dim3 block(NTHR);
    hipLaunchKernelGGL(dhsrnn_fused, grid, block, 0, stream,
                       x, r1_bw, r1_bb, r1_ow, r1_ob,
                       r2_bw, r2_bb, r2_ow, r2_ob, cw, cb, out);
}

// Round 3
// 399.913 us; speedup vs baseline: 86.0460x; 5.9280x over previous
//
#include <hip/hip_runtime.h>

// SimpleDHSRNN fused forward, round 3: split-bf16 MFMA path.
// Block = 256 threads = 4 waves; each block owns 32 batch rows; grid = 256.
// Per step: 4 matmuls (M=32) on matrix cores, 3 MFMAs per tile (hi/lo split),
// weights register-resident, activations transposed through LDS as bf16 hi/lo planes.

typedef float f32x4 __attribute__((ext_vector_type(4)));
typedef short s16x8 __attribute__((ext_vector_type(8)));

#define MFMA16(a, b, c) __builtin_amdgcn_mfma_f32_16x16x32_bf16((a), (b), (c), 0, 0, 0)

#define T_STEPS 196

// LDS pool offsets (ushort units). Row strides padded to multiples of 8 ushorts (16B).
#define A3H 0        // h-planes [32][104]: cols 0-31 = h1, 32-95 = h2
#define A3L 3328
#define A2H 6656     // ns1 planes [32][72] (cols 0-63)
#define A2L 8960
#define A4H 11264    // ns2 planes [32][136] (cols 0-127)
#define A4L 15616
#define XB  19968    // 32 floats (x_t per batch row)
#define POOL_SZ 20032

__device__ __forceinline__ void split8g(const float* __restrict__ p, s16x8& h, s16x8& l) {
#pragma unroll
    for (int i = 0; i < 8; ++i) {
        float v = p[i];
        unsigned b = __float_as_uint(v);
        float lo = v - __uint_as_float(b & 0xFFFF0000u);
        h[i] = (short)(b >> 16);
        l[i] = (short)(__float_as_uint(lo) >> 16);
    }
}

__global__ __launch_bounds__(256, 1)
void dhsrnn_mfma(const float* __restrict__ x,
                 const float* __restrict__ r1_bw, const float* __restrict__ r1_bb,
                 const float* __restrict__ r1_ow, const float* __restrict__ r1_ob,
                 const float* __restrict__ r2_bw, const float* __restrict__ r2_bb,
                 const float* __restrict__ r2_ow, const float* __restrict__ r2_ob,
                 const float* __restrict__ cw,    const float* __restrict__ cb,
                 float* __restrict__ out)
{
    __shared__ __align__(16) unsigned short pool[POOL_SZ];

    const int tid = threadIdx.x;
    const int w   = tid >> 6;    // wave 0..3
    const int l   = tid & 63;
    const int li  = l & 15;
    const int g   = l >> 4;
    const int blk = blockIdx.x;

    // ---- zero h-planes (h1_0 = h2_0 = 0), stage x_0 ----
    for (int i = tid; i < 2 * 3328; i += 256) pool[A3H + i] = 0;
    if (tid < 32) *(float*)&pool[XB + 2 * tid] = x[(blk * 32 + tid) * 784];

    // ---- register-resident weight fragments (hi/lo bf16), loaded once ----
    // S1: bo1 = h1 @ W1h^T (+ x*wx + b). W1[n][k] = r1_bw[n*33 + 1 + k], K=32.
    const int n1 = w * 16 + li;
    s16x8 B1h, B1l;
    split8g(r1_bw + n1 * 33 + 1 + g * 8, B1h, B1l);
    const float wxn = r1_bw[n1 * 33];
    const float b1n = r1_bb[n1];
    const float a1  = (w < 2) ? 0.3f : 0.7f;

    // S2: h1 = relu(ns1 @ ow1^T + ob1). Tile (mt2, nt2) per wave. K=64.
    const int mt2 = w >> 1, nt2 = w & 1;
    const int n2 = nt2 * 16 + li;
    s16x8 B2h[2], B2l[2];
#pragma unroll
    for (int kt = 0; kt < 2; ++kt) split8g(r1_ow + n2 * 64 + kt * 32 + g * 8, B2h[kt], B2l[kt]);
    const float ob1n = r1_ob[n2];

    // S3: bo2 = [h1,h2] @ W2b^T + b. N=128, K=96; wave handles n-tiles {2w, 2w+1}.
    s16x8 B3h[2][3], B3l[2][3];
    float b2n[2];
#pragma unroll
    for (int fn = 0; fn < 2; ++fn) {
        int n3 = (2 * w + fn) * 16 + li;
        b2n[fn] = r2_bb[n3];
#pragma unroll
        for (int kt = 0; kt < 3; ++kt)
            split8g(r2_bw + n3 * 96 + kt * 32 + g * 8, B3h[fn][kt], B3l[fn][kt]);
    }
    const float a2 = (w < 2) ? 0.3f : 0.7f;

    // S4: h2 = relu(ns2 @ ow2^T + ob2). N=64, K=128; n-tile w.
    const int n4 = w * 16 + li;
    s16x8 B4h[4], B4l[4];
#pragma unroll
    for (int kt = 0; kt < 4; ++kt) split8g(r2_ow + n4 * 128 + kt * 32 + g * 8, B4h[kt], B4l[kt]);
    const float ob2n = r2_ob[n4];

    // persistent EMA states (fp32, accumulator layout: row m = mt*16 + 4g + r)
    f32x4 s1a[2];
    f32x4 s2a[2][2];
#pragma unroll
    for (int mt = 0; mt < 2; ++mt) {
        s1a[mt] = (f32x4){0.f, 0.f, 0.f, 0.f};
#pragma unroll
        for (int fn = 0; fn < 2; ++fn) s2a[mt][fn] = (f32x4){0.f, 0.f, 0.f, 0.f};
    }

    __syncthreads();

#pragma unroll 1
    for (int t = 0; t < T_STEPS; ++t) {
        // ---- S1: cell1 branch (MFMA over h1) + x rank-1 + EMA -> write ns1 planes ----
        f32x4 d1[2];
#pragma unroll
        for (int mt = 0; mt < 2; ++mt) {
            f32x4 d = {0.f, 0.f, 0.f, 0.f};
            const s16x8 ah = *(const s16x8*)&pool[A3H + (mt * 16 + li) * 104 + g * 8];
            const s16x8 al = *(const s16x8*)&pool[A3L + (mt * 16 + li) * 104 + g * 8];
            d = MFMA16(ah, B1h, d);
            d = MFMA16(al, B1h, d);
            d = MFMA16(ah, B1l, d);
            d1[mt] = d;
        }
#pragma unroll
        for (int mt = 0; mt < 2; ++mt) {
            const f32x4 xv = *(const f32x4*)&pool[XB + 2 * (mt * 16 + 4 * g)];
#pragma unroll
            for (int r = 0; r < 4; ++r) {
                int m = mt * 16 + 4 * g + r;
                float bo = d1[mt][r] + b1n + wxn * xv[r];
                float ns = a1 * s1a[mt][r] + (1.0f - a1) * bo;
                s1a[mt][r] = ns;
                unsigned b = __float_as_uint(ns);
                float lo = ns - __uint_as_float(b & 0xFFFF0000u);
                int ad = m * 72 + n1;
                pool[A2H + ad] = (unsigned short)(b >> 16);
                pool[A2L + ad] = (unsigned short)(__float_as_uint(lo) >> 16);
            }
        }
        __syncthreads();

        // ---- S2: h1 = relu(ns1 @ W2^T + ob1) -> write h1 into A3 cols 0-31 ----
        {
            f32x4 d = {0.f, 0.f, 0.f, 0.f};
#pragma unroll
            for (int kt = 0; kt < 2; ++kt) {
                const s16x8 ah = *(const s16x8*)&pool[A2H + (mt2 * 16 + li) * 72 + kt * 32 + g * 8];
                const s16x8 al = *(const s16x8*)&pool[A2L + (mt2 * 16 + li) * 72 + kt * 32 + g * 8];
                d = MFMA16(ah, B2h[kt], d);
                d = MFMA16(al, B2h[kt], d);
                d = MFMA16(ah, B2l[kt], d);
            }
#pragma unroll
            for (int r = 0; r < 4; ++r) {
                int m = mt2 * 16 + 4 * g + r;
                float h = fmaxf(d[r] + ob1n, 0.0f);
                unsigned b = __float_as_uint(h);
                float lo = h - __uint_as_float(b & 0xFFFF0000u);
                int ad = m * 104 + n2;
                pool[A3H + ad] = (unsigned short)(b >> 16);
                pool[A3L + ad] = (unsigned short)(__float_as_uint(lo) >> 16);
            }
        }
        __syncthreads();

        // ---- S3: cell2 branch over [h1|h2] + EMA -> write ns2 planes ----
        {
            f32x4 d3[2][2];
#pragma unroll
            for (int mt = 0; mt < 2; ++mt)
#pragma unroll
                for (int fn = 0; fn < 2; ++fn) d3[mt][fn] = (f32x4){0.f, 0.f, 0.f, 0.f};
#pragma unroll
            for (int kt = 0; kt < 3; ++kt) {
#pragma unroll
                for (int mt = 0; mt < 2; ++mt) {
                    const s16x8 ah = *(const s16x8*)&pool[A3H + (mt * 16 + li) * 104 + kt * 32 + g * 8];
                    const s16x8 al = *(const s16x8*)&pool[A3L + (mt * 16 + li) * 104 + kt * 32 + g * 8];
#pragma unroll
                    for (int fn = 0; fn < 2; ++fn) {
                        d3[mt][fn] = MFMA16(ah, B3h[fn][kt], d3[mt][fn]);
                        d3[mt][fn] = MFMA16(al, B3h[fn][kt], d3[mt][fn]);
                        d3[mt][fn] = MFMA16(ah, B3l[fn][kt], d3[mt][fn]);
                    }
                }
            }
#pragma unroll
            for (int mt = 0; mt < 2; ++mt)
#pragma unroll
                for (int fn = 0; fn < 2; ++fn)
#pragma unroll
                    for (int r = 0; r < 4; ++r) {
                        int m = mt * 16 + 4 * g + r;
                        float bo = d3[mt][fn][r] + b2n[fn];
                        float ns = a2 * s2a[mt][fn][r] + (1.0f - a2) * bo;
                        s2a[mt][fn][r] = ns;
                        unsigned b = __float_as_uint(ns);
                        float lo = ns - __uint_as_float(b & 0xFFFF0000u);
                        int ad = m * 136 + (2 * w + fn) * 16 + li;
                        pool[A4H + ad] = (unsigned short)(b >> 16);
                        pool[A4L + ad] = (unsigned short)(__float_as_uint(lo) >> 16);
                    }
        }
        __syncthreads();

        // ---- S4: h2 = relu(ns2 @ W4^T + ob2) -> write h2 into A3 cols 32-95 ----
        {
            f32x4 d4[2];
#pragma unroll
            for (int mt = 0; mt < 2; ++mt) d4[mt] = (f32x4){0.f, 0.f, 0.f, 0.f};
#pragma unroll
            for (int kt = 0; kt < 4; ++kt) {
#pragma unroll
                for (int mt = 0; mt < 2; ++mt) {
                    const s16x8 ah = *(const s16x8*)&pool[A4H + (mt * 16 + li) * 136 + kt * 32 + g * 8];
                    const s16x8 al = *(const s16x8*)&pool[A4L + (mt * 16 + li) * 136 + kt * 32 + g * 8];
                    d4[mt] = MFMA16(ah, B4h[kt], d4[mt]);
                    d4[mt] = MFMA16(al, B4h[kt], d4[mt]);
                    d4[mt] = MFMA16(ah, B4l[kt], d4[mt]);
                }
            }
#pragma unroll
            for (int mt = 0; mt < 2; ++mt)
#pragma unroll
                for (int r = 0; r < 4; ++r) {
                    int m = mt * 16 + 4 * g + r;
                    float h = fmaxf(d4[mt][r] + ob2n, 0.0f);
                    unsigned b = __float_as_uint(h);
                    float lo = h - __uint_as_float(b & 0xFFFF0000u);
                    int ad = m * 104 + 32 + n4;
                    pool[A3H + ad] = (unsigned short)(b >> 16);
                    pool[A3L + ad] = (unsigned short)(__float_as_uint(lo) >> 16);
                    if (t == T_STEPS - 1)
                        *(float*)&pool[A2H + 2 * (m * 64 + n4)] = h;   // fp32 h2 for classifier
                }
            if (w == 0 && l < 32 && t + 1 < T_STEPS)
                *(float*)&pool[XB + 2 * l] = x[(blk * 32 + l) * 784 + 4 * (t + 1)];
        }
        __syncthreads();
    }

    // ---- classifier: out[b][c] = h2 . cw[c] + cb[c] ----
    {
        const float* hb = (const float*)&pool[A2H];
        int e  = tid & 31;
        int c0 = tid >> 5;
        for (int c = c0; c < 10; c += 8) {
            float acc = cb[c];
            for (int dd = 0; dd < 64; ++dd)
                acc += hb[e * 64 + dd] * cw[c * 64 + dd];
            out[(blk * 32 + e) * 10 + c] = acc;
        }
    }
}

extern "C" void kernel_launch(void* const* d_in, const int* in_sizes, int n_in,
                              void* d_out, int out_size, void* d_ws, size_t ws_size,
                              hipStream_t stream) {
    const float* x     = (const float*)d_in[0];
    const float* r1_bw = (const float*)d_in[1];
    const float* r1_bb = (const float*)d_in[2];
    const float* r1_ow = (const float*)d_in[3];
    const float* r1_ob = (const float*)d_in[4];
    const float* r2_bw = (const float*)d_in[5];
    const float* r2_bb = (const float*)d_in[6];
    const float* r2_ow = (const float*)d_in[7];
    const float* r2_ob = (const float*)d_in[8];
    const float* cw    = (const float*)d_in[9];
    const float* cb    = (const float*)d_in[10];
    float* out = (float*)d_out;

    dim3 grid(256);
    dim3 block(256);
    hipLaunchKernelGGL(dhsrnn_mfma, grid, block, 0, stream,
                       x, r1_bw, r1_bb, r1_ow, r1_ob,
                       r2_bw, r2_bb, r2_ow, r2_ob, cw, cb, out);
}

// Round 4
// 316.092 us; speedup vs baseline: 108.8636x; 1.2652x over previous
//
#include <hip/hip_runtime.h>

// SimpleDHSRNN fused forward, round 4: split-bf16 MFMA, M=16 blocks, 2 blocks/CU.
// grid = 512 blocks x 16 batch rows; block = 256 threads = 4 waves (N-split).
// Weights register-resident (hi/lo bf16); activations through LDS hi/lo planes.

typedef float f32x4 __attribute__((ext_vector_type(4)));
typedef short s16x8 __attribute__((ext_vector_type(8)));

#define MFMA16(a, b, c) __builtin_amdgcn_mfma_f32_16x16x32_bf16((a), (b), (c), 0, 0, 0)

#define T_STEPS 196

// LDS pool offsets (ushort units)
#define A3H 0        // h planes [16][104]: cols 0-31 h1, 32-95 h2
#define A3L 1664
#define A2H 3328     // ns1 planes [16][72] (cols 0-63)
#define A2L 4480
#define A4H 5632     // ns2 planes [16][136] (cols 0-127)
#define A4L 7808
#define XB  9984     // 16 floats (x_t per batch row)
#define POOL_SZ 10016
// classifier fp32 h2 [16][67] aliases A2H.. (written at last step only)

__device__ __forceinline__ void split8g(const float* __restrict__ p, s16x8& h, s16x8& l) {
#pragma unroll
    for (int i = 0; i < 8; ++i) {
        float v = p[i];
        unsigned b = __float_as_uint(v);
        float lo = v - __uint_as_float(b & 0xFFFF0000u);
        h[i] = (short)(b >> 16);
        l[i] = (short)(__float_as_uint(lo) >> 16);
    }
}

__global__ __launch_bounds__(256, 2)
void dhsrnn_mfma(const float* __restrict__ x,
                 const float* __restrict__ r1_bw, const float* __restrict__ r1_bb,
                 const float* __restrict__ r1_ow, const float* __restrict__ r1_ob,
                 const float* __restrict__ r2_bw, const float* __restrict__ r2_bb,
                 const float* __restrict__ r2_ow, const float* __restrict__ r2_ob,
                 const float* __restrict__ cw,    const float* __restrict__ cb,
                 float* __restrict__ out)
{
    __shared__ __align__(16) unsigned short pool[POOL_SZ];
    float* const poolf_x = (float*)&pool[XB];

    const int tid = threadIdx.x;
    const int w   = tid >> 6;    // wave 0..3
    const int l   = tid & 63;
    const int li  = l & 15;
    const int g   = l >> 4;
    const int row0 = blockIdx.x * 16;

    // ---- zero h planes (h1_0 = h2_0 = 0), stage x_0 ----
    for (int i = tid; i < 2 * 1664; i += 256) pool[A3H + i] = 0;
    if (tid < 16) poolf_x[tid] = x[(row0 + tid) * 784];

    // ---- register-resident weight fragments (hi/lo bf16) ----
    // S1: bo1 = h1 @ W1h^T (+ x*wx + b). N=64, K=32.
    const int n1 = w * 16 + li;
    s16x8 B1h, B1l;
    split8g(r1_bw + n1 * 33 + 1 + g * 8, B1h, B1l);
    const float wxn = r1_bw[n1 * 33];
    const float b1n = r1_bb[n1];
    const float a1  = (w < 2) ? 0.3f : 0.7f;

    // S2: h1 = relu(ns1 @ ow1^T + ob1). N=32 (waves 0,1), K=64.
    const int n2 = (w & 1) * 16 + li;
    s16x8 B2h[2], B2l[2];
    float ob1n = 0.0f;
    if (w < 2) {
#pragma unroll
        for (int kt = 0; kt < 2; ++kt) split8g(r1_ow + n2 * 64 + kt * 32 + g * 8, B2h[kt], B2l[kt]);
        ob1n = r1_ob[n2];
    }

    // S3: bo2 = [h1,h2] @ W2b^T + b. N=128 (2 n-tiles/wave), K=96.
    s16x8 B3h[2][3], B3l[2][3];
    float b2n[2];
#pragma unroll
    for (int fn = 0; fn < 2; ++fn) {
        int n3 = (2 * w + fn) * 16 + li;
        b2n[fn] = r2_bb[n3];
#pragma unroll
        for (int kt = 0; kt < 3; ++kt)
            split8g(r2_bw + n3 * 96 + kt * 32 + g * 8, B3h[fn][kt], B3l[fn][kt]);
    }
    const float a2 = (w < 2) ? 0.3f : 0.7f;

    // S4: h2 = relu(ns2 @ ow2^T + ob2). N=64, K=128.
    const int n4 = w * 16 + li;
    s16x8 B4h[4], B4l[4];
#pragma unroll
    for (int kt = 0; kt < 4; ++kt) split8g(r2_ow + n4 * 128 + kt * 32 + g * 8, B4h[kt], B4l[kt]);
    const float ob2n = r2_ob[n4];

    // persistent EMA states (fp32, acc layout: row m = 4g + r)
    f32x4 s1a = {0.f, 0.f, 0.f, 0.f};
    f32x4 s2a[2];
    s2a[0] = (f32x4){0.f, 0.f, 0.f, 0.f};
    s2a[1] = (f32x4){0.f, 0.f, 0.f, 0.f};

    __syncthreads();

#pragma unroll 1
    for (int t = 0; t < T_STEPS; ++t) {
        // prefetch next x into a register (latency hidden under S1-S4)
        float xnext = 0.0f;
        if (tid < 16 && t + 1 < T_STEPS)
            xnext = x[(row0 + tid) * 784 + 4 * (t + 1)];

        // ---- S1: cell1 branch (MFMA over h1) + x rank-1 + EMA -> ns1 planes ----
        {
            const f32x4 xv = *(const f32x4*)(poolf_x + 4 * g);
            const s16x8 ah = *(const s16x8*)&pool[A3H + li * 104 + g * 8];
            const s16x8 al = *(const s16x8*)&pool[A3L + li * 104 + g * 8];
            f32x4 d = {0.f, 0.f, 0.f, 0.f};
            d = MFMA16(ah, B1h, d);
            d = MFMA16(al, B1h, d);
            d = MFMA16(ah, B1l, d);
#pragma unroll
            for (int r = 0; r < 4; ++r) {
                int m = 4 * g + r;
                float bo = d[r] + b1n + wxn * xv[r];
                float ns = a1 * s1a[r] + (1.0f - a1) * bo;
                s1a[r] = ns;
                unsigned b = __float_as_uint(ns);
                float lo = ns - __uint_as_float(b & 0xFFFF0000u);
                int ad = m * 72 + n1;
                pool[A2H + ad] = (unsigned short)(b >> 16);
                pool[A2L + ad] = (unsigned short)(__float_as_uint(lo) >> 16);
            }
        }
        __syncthreads();

        // ---- S2: h1 = relu(ns1 @ ow1^T + ob1) -> h1 into A3 cols 0-31 ----
        if (w < 2) {
            f32x4 d = {0.f, 0.f, 0.f, 0.f};
#pragma unroll
            for (int kt = 0; kt < 2; ++kt) {
                const s16x8 ah = *(const s16x8*)&pool[A2H + li * 72 + kt * 32 + g * 8];
                const s16x8 al = *(const s16x8*)&pool[A2L + li * 72 + kt * 32 + g * 8];
                d = MFMA16(ah, B2h[kt], d);
                d = MFMA16(al, B2h[kt], d);
                d = MFMA16(ah, B2l[kt], d);
            }
#pragma unroll
            for (int r = 0; r < 4; ++r) {
                int m = 4 * g + r;
                float h = fmaxf(d[r] + ob1n, 0.0f);
                unsigned b = __float_as_uint(h);
                float lo = h - __uint_as_float(b & 0xFFFF0000u);
                int ad = m * 104 + n2;
                pool[A3H + ad] = (unsigned short)(b >> 16);
                pool[A3L + ad] = (unsigned short)(__float_as_uint(lo) >> 16);
            }
        }
        __syncthreads();

        // ---- S3: cell2 branch over [h1|h2] + EMA -> ns2 planes ----
        {
            f32x4 d3[2];
            d3[0] = (f32x4){0.f, 0.f, 0.f, 0.f};
            d3[1] = (f32x4){0.f, 0.f, 0.f, 0.f};
#pragma unroll
            for (int kt = 0; kt < 3; ++kt) {
                const s16x8 ah = *(const s16x8*)&pool[A3H + li * 104 + kt * 32 + g * 8];
                const s16x8 al = *(const s16x8*)&pool[A3L + li * 104 + kt * 32 + g * 8];
#pragma unroll
                for (int fn = 0; fn < 2; ++fn) {
                    d3[fn] = MFMA16(ah, B3h[fn][kt], d3[fn]);
                    d3[fn] = MFMA16(al, B3h[fn][kt], d3[fn]);
                    d3[fn] = MFMA16(ah, B3l[fn][kt], d3[fn]);
                }
            }
#pragma unroll
            for (int fn = 0; fn < 2; ++fn) {
                int n3 = (2 * w + fn) * 16 + li;
#pragma unroll
                for (int r = 0; r < 4; ++r) {
                    int m = 4 * g + r;
                    float bo = d3[fn][r] + b2n[fn];
                    float ns = a2 * s2a[fn][r] + (1.0f - a2) * bo;
                    s2a[fn][r] = ns;
                    unsigned b = __float_as_uint(ns);
                    float lo = ns - __uint_as_float(b & 0xFFFF0000u);
                    int ad = m * 136 + n3;
                    pool[A4H + ad] = (unsigned short)(b >> 16);
                    pool[A4L + ad] = (unsigned short)(__float_as_uint(lo) >> 16);
                }
            }
        }
        __syncthreads();

        // ---- S4: h2 = relu(ns2 @ ow2^T + ob2) -> h2 into A3 cols 32-95 ----
        {
            f32x4 d4 = {0.f, 0.f, 0.f, 0.f};
#pragma unroll
            for (int kt = 0; kt < 4; ++kt) {
                const s16x8 ah = *(const s16x8*)&pool[A4H + li * 136 + kt * 32 + g * 8];
                const s16x8 al = *(const s16x8*)&pool[A4L + li * 136 + kt * 32 + g * 8];
                d4 = MFMA16(ah, B4h[kt], d4);
                d4 = MFMA16(al, B4h[kt], d4);
                d4 = MFMA16(ah, B4l[kt], d4);
            }
            float* const hcf = (float*)&pool[A2H];   // classifier h2 buffer [16][67]
#pragma unroll
            for (int r = 0; r < 4; ++r) {
                int m = 4 * g + r;
                float h = fmaxf(d4[r] + ob2n, 0.0f);
                unsigned b = __float_as_uint(h);
                float lo = h - __uint_as_float(b & 0xFFFF0000u);
                int ad = m * 104 + 32 + n4;
                pool[A3H + ad] = (unsigned short)(b >> 16);
                pool[A3L + ad] = (unsigned short)(__float_as_uint(lo) >> 16);
                if (t == T_STEPS - 1) hcf[m * 67 + n4] = h;
            }
            if (tid < 16) poolf_x[tid] = xnext;   // commit prefetched x(t+1)
        }
        __syncthreads();
    }

    // ---- classifier: out[b][c] = h2 . cw[c] + cb[c] ----
    {
        const float* hcf = (const float*)&pool[A2H];
        const int c = tid >> 4;
        const int e = tid & 15;
        if (c < 10) {
            float acc = cb[c];
#pragma unroll 4
            for (int dd = 0; dd < 64; ++dd)
                acc += hcf[e * 67 + dd] * cw[c * 64 + dd];
            out[(row0 + e) * 10 + c] = acc;
        }
    }
}

extern "C" void kernel_launch(void* const* d_in, const int* in_sizes, int n_in,
                              void* d_out, int out_size, void* d_ws, size_t ws_size,
                              hipStream_t stream) {
    const float* x     = (const float*)d_in[0];
    const float* r1_bw = (const float*)d_in[1];
    const float* r1_bb = (const float*)d_in[2];
    const float* r1_ow = (const float*)d_in[3];
    const float* r1_ob = (const float*)d_in[4];
    const float* r2_bw = (const float*)d_in[5];
    const float* r2_bb = (const float*)d_in[6];
    const float* r2_ow = (const float*)d_in[7];
    const float* r2_ob = (const float*)d_in[8];
    const float* cw    = (const float*)d_in[9];
    const float* cb    = (const float*)d_in[10];
    float* out = (float*)d_out;

    dim3 grid(512);
    dim3 block(256);
    hipLaunchKernelGGL(dhsrnn_mfma, grid, block, 0, stream,
                       x, r1_bw, r1_bb, r1_ow, r1_ob,
                       r2_bw, r2_bb, r2_ow, r2_ob, cw, cb, out);
}